// Round 1
// baseline (261.856 us; speedup 1.0000x reference)
//
#include <hip/hip_runtime.h>

// MLPAttention: B=4, LQ=128, LK=1024, D=512, UNITS=256, fp32.
// K1: q_proj = query@W_q^T (row-major), kT = (key@W_k^T) transposed to [b][u][j]
// K2: scores via tanh(x)=1-2/(1+e^2x), e^{2(q+k)}=e^{2q}*e^{2k}; masked softmax
// K3: out = attn @ value, K truncated at valid_len (attn==0 beyond)

__global__ __launch_bounds__(256) void gemm_nt(const float* __restrict__ X,
                                               const float* __restrict__ W,
                                               float* __restrict__ out, int mode) {
  // C[M,256] = X[M,512] @ W[256,512]^T ; BM=BN=64, BK=32, 4x4 micro-tile
  __shared__ float Xs[64 * 36];
  __shared__ float Ws[64 * 36];
  const int tid = threadIdx.x;
  const int m0 = blockIdx.x * 64;
  const int u0 = blockIdx.y * 64;
  const int tx = tid & 15, ty = tid >> 4;
  const int ti = ty * 4, tj = tx * 4;
  float c[4][4] = {};

  for (int kb = 0; kb < 512; kb += 32) {
    __syncthreads();
#pragma unroll
    for (int p = 0; p < 2; ++p) {
      int idx = tid + p * 256;
      int row = idx >> 3, kc = (idx & 7) * 4;
      float4 xv = *(const float4*)(X + (m0 + row) * 512 + kb + kc);
      *(float4*)(Xs + row * 36 + kc) = xv;
      float4 wv = *(const float4*)(W + (u0 + row) * 512 + kb + kc);
      *(float4*)(Ws + row * 36 + kc) = wv;
    }
    __syncthreads();
#pragma unroll
    for (int kk = 0; kk < 32; kk += 4) {
      float4 a[4], b[4];
#pragma unroll
      for (int i = 0; i < 4; ++i) a[i] = *(const float4*)(Xs + (ti + i) * 36 + kk);
#pragma unroll
      for (int j = 0; j < 4; ++j) b[j] = *(const float4*)(Ws + (tj + j) * 36 + kk);
#pragma unroll
      for (int i = 0; i < 4; ++i)
#pragma unroll
        for (int j = 0; j < 4; ++j) {
          c[i][j] = fmaf(a[i].x, b[j].x, c[i][j]);
          c[i][j] = fmaf(a[i].y, b[j].y, c[i][j]);
          c[i][j] = fmaf(a[i].z, b[j].z, c[i][j]);
          c[i][j] = fmaf(a[i].w, b[j].w, c[i][j]);
        }
    }
  }

  if (mode == 0) {
    // q_proj[r][u], r = b*128+i
#pragma unroll
    for (int i = 0; i < 4; ++i) {
      float4 v4 = make_float4(c[i][0], c[i][1], c[i][2], c[i][3]);
      *(float4*)(out + (m0 + ti + i) * 256 + u0 + tj) = v4;
    }
  } else {
    // kT[b][u][j], r = b*1024 + j; tile rows stay within one b (1024%64==0)
    int r = m0 + ti;
    int b = r >> 10, j = r & 1023;
#pragma unroll
    for (int jj = 0; jj < 4; ++jj) {
      float4 v4 = make_float4(c[0][jj], c[1][jj], c[2][jj], c[3][jj]);
      *(float4*)(out + b * 262144 + (u0 + tj + jj) * 1024 + j) = v4;
    }
  }
}

__device__ __forceinline__ float block_reduce(float v, int op, float* red) {
#pragma unroll
  for (int off = 32; off > 0; off >>= 1) {
    float o = __shfl_xor(v, off, 64);
    v = op ? fmaxf(v, o) : (v + o);
  }
  __syncthreads();  // protects red reuse across calls (and QV visibility on 1st call)
  if ((threadIdx.x & 63) == 0) red[threadIdx.x >> 6] = v;
  __syncthreads();
  return op ? fmaxf(fmaxf(red[0], red[1]), fmaxf(red[2], red[3]))
            : (red[0] + red[1] + red[2] + red[3]);
}

__global__ __launch_bounds__(256) void scores_softmax(
    const float* __restrict__ qproj, const float* __restrict__ kT,
    const float* __restrict__ vvec, const int* __restrict__ valid_len,
    float* __restrict__ attn) {
  // one block per (b, pair of query rows); 256 threads, thread t handles j = t+256m
  __shared__ float4 QV[256];  // (e^{2q0}, e^{2q1}, -2*v, 0)
  __shared__ float red[4];
  const int tid = threadIdx.x;
  const int b = blockIdx.x >> 6;
  const int i0 = (blockIdx.x & 63) * 2;
  const int vl = valid_len[b];

  const float q0 = qproj[(b * 128 + i0) * 256 + tid];
  const float q1 = qproj[(b * 128 + i0 + 1) * 256 + tid];
  const float vv = vvec[tid];
  QV[tid] = make_float4(__expf(2.f * q0), __expf(2.f * q1), -2.f * vv, 0.f);
  const float SV = block_reduce(vv, 0, red);  // sum of v over u

  float s0[4], s1[4];
  const float* kbase = kT + b * 262144;
  for (int m = 0; m < 4; ++m) {
    const int j = tid + m * 256;
    if (j < vl) {
      float a0 = 0.f, a1 = 0.f;
      const float* kp = kbase + j;
#pragma unroll 8
      for (int u = 0; u < 256; ++u) {
        float kv = kp[u << 10];           // coalesced across lanes
        float ek = __expf(2.f * kv);      // shared by both query rows
        float4 qv = QV[u];                // LDS broadcast
        float r0 = __builtin_amdgcn_rcpf(fmaf(qv.x, ek, 1.f));
        float r1 = __builtin_amdgcn_rcpf(fmaf(qv.y, ek, 1.f));
        a0 = fmaf(qv.z, r0, a0);          // accumulates -2*v/(1+e^{2x})
        a1 = fmaf(qv.z, r1, a1);
      }
      s0[m] = SV + a0;  // = sum_u v*tanh(q0+k)
      s1[m] = SV + a1;
    } else {
      s0[m] = -1e6f;
      s1[m] = -1e6f;
    }
  }

  // softmax row i0
  float mx = fmaxf(fmaxf(s0[0], s0[1]), fmaxf(s0[2], s0[3]));
  float M0 = block_reduce(mx, 1, red);
  float sum = 0.f;
#pragma unroll
  for (int m = 0; m < 4; ++m) {
    int j = tid + m * 256;
    s0[m] = (j < vl) ? __expf(s0[m] - M0) : 0.f;
    sum += s0[m];
  }
  float S0 = block_reduce(sum, 0, red);
  float rs0 = __builtin_amdgcn_rcpf(S0);
  float* arow0 = attn + (b * 128 + i0) * 1024;
#pragma unroll
  for (int m = 0; m < 4; ++m) arow0[tid + m * 256] = s0[m] * rs0;

  // softmax row i0+1
  mx = fmaxf(fmaxf(s1[0], s1[1]), fmaxf(s1[2], s1[3]));
  float M1 = block_reduce(mx, 1, red);
  sum = 0.f;
#pragma unroll
  for (int m = 0; m < 4; ++m) {
    int j = tid + m * 256;
    s1[m] = (j < vl) ? __expf(s1[m] - M1) : 0.f;
    sum += s1[m];
  }
  float S1 = block_reduce(sum, 0, red);
  float rs1 = __builtin_amdgcn_rcpf(S1);
  float* arow1 = attn + (b * 128 + i0 + 1) * 1024;
#pragma unroll
  for (int m = 0; m < 4; ++m) arow1[tid + m * 256] = s1[m] * rs1;
}

__global__ __launch_bounds__(256) void attn_value(
    const float* __restrict__ attn, const float* __restrict__ value,
    const int* __restrict__ valid_len, float* __restrict__ out) {
  // BM=16, BN=64, BK=32; K-loop truncated at valid_len
  __shared__ float As[16 * 33];
  __shared__ float Bs[32 * 64];
  const int tid = threadIdx.x;
  const int b = blockIdx.x >> 6;
  const int it = (blockIdx.x >> 3) & 7;
  const int nt = blockIdx.x & 7;
  const int i0 = it * 16, n0 = nt * 64;
  const int vl = valid_len[b];
  const int ktiles = (vl + 31) >> 5;
  const float* A = attn + (b * 128 + i0) * 1024;
  const float* B = value + b * 1024 * 512 + n0;
  const int rowt = tid >> 4, colg = (tid & 15) * 4;
  float4 acc = make_float4(0.f, 0.f, 0.f, 0.f);

  for (int kb = 0; kb < ktiles; ++kb) {
    __syncthreads();
    {
      int lin = tid * 2, row = lin >> 5, k = lin & 31;
      float2 a2 = *(const float2*)(A + row * 1024 + kb * 32 + k);
      As[row * 33 + k] = a2.x;
      As[row * 33 + k + 1] = a2.y;
#pragma unroll
      for (int p = 0; p < 2; ++p) {
        int idx = tid + p * 256;
        int brow = idx >> 4, bcol = (idx & 15) * 4;
        *(float4*)(Bs + brow * 64 + bcol) =
            *(const float4*)(B + (kb * 32 + brow) * 512 + bcol);
      }
    }
    __syncthreads();
#pragma unroll
    for (int kk = 0; kk < 32; ++kk) {
      float a = As[rowt * 33 + kk];
      float4 b4 = *(const float4*)(Bs + kk * 64 + colg);
      acc.x = fmaf(a, b4.x, acc.x);
      acc.y = fmaf(a, b4.y, acc.y);
      acc.z = fmaf(a, b4.z, acc.z);
      acc.w = fmaf(a, b4.w, acc.w);
    }
  }
  *(float4*)(out + (b * 128 + i0 + rowt) * 512 + n0 + colg) = acc;
}

extern "C" void kernel_launch(void* const* d_in, const int* in_sizes, int n_in,
                              void* d_out, int out_size, void* d_ws, size_t ws_size,
                              hipStream_t stream) {
  const float* query = (const float*)d_in[0];
  const float* key   = (const float*)d_in[1];
  const float* value = (const float*)d_in[2];
  const int*   vlen  = (const int*)d_in[3];
  const float* W_q   = (const float*)d_in[4];
  const float* W_k   = (const float*)d_in[5];
  const float* v     = (const float*)d_in[6];
  float* out = (float*)d_out;

  char* ws = (char*)d_ws;
  float* qproj = (float*)ws;                                   // 512*256 f32 (512 KB)
  float* kT    = (float*)(ws + 512 * 1024);                    // 4*256*1024 f32 (4 MB), [b][u][j]
  float* attn  = (float*)(ws + 512 * 1024 + 4 * 1024 * 1024);  // 4*128*1024 f32 (2 MB)

  gemm_nt<<<dim3(8, 4), 256, 0, stream>>>(query, W_q, qproj, 0);
  gemm_nt<<<dim3(64, 4), 256, 0, stream>>>(key, W_k, kT, 1);
  scores_softmax<<<256, 256, 0, stream>>>(qproj, kT, v, vlen, attn);
  attn_value<<<256, 256, 0, stream>>>(attn, value, vlen, out);
}

// Round 2
// 169.738 us; speedup vs baseline: 1.5427x; 1.5427x over previous
//
#include <hip/hip_runtime.h>

// MLPAttention B=4, LQ=128, LK=1024, D=512, U=256, fp32.
// scores(i,j) = sum_u v_u * tanh(q_iu + k_uj);  tanh(x) = 1 - 2/(1+e^{2x})
// => scores = SV - 2*sum_u v_u/(1 + Eq_iu*Ek_uj),  Eq=e^{2q}, Ek=e^{2k}
// K1: fused projection GEMM (fp32 vector), epilogue exp(2x):
//     Eq[512][256] row-major; EkT[4][256][1024] transposed.
// K2: scores + masked softmax fused (1024 thr/block, 16 waves).
// K3: out = attn @ value, wave-per-block, K truncated at valid_len.

#define EQ_OFF   0
#define EKT_OFF  (512 * 256)            // floats
#define ATTN_OFF (EKT_OFF + 4 * 256 * 1024)

__global__ __launch_bounds__(128) void proj_gemm(
    const float* __restrict__ query, const float* __restrict__ key,
    const float* __restrict__ W_q, const float* __restrict__ W_k,
    float* __restrict__ Eq, float* __restrict__ EkT) {
  // BM=64, BN=32, BK=32, 128 threads (2 waves), 4x4 microtile.
  // lane map: colpos = tid&7, rowpos = tid>>3  -> 8-way same-address LDS sharing.
  __shared__ float Xs[64 * 36];
  __shared__ float Ws[32 * 36];
  const int tid = threadIdx.x;
  const bool qpart = blockIdx.x < 8;
  const float* X = qpart ? query : key;
  const float* W = qpart ? W_q : W_k;
  const int m0 = (qpart ? blockIdx.x : (blockIdx.x - 8)) * 64;
  const int u0 = blockIdx.y * 32;
  const int ti = (tid >> 3) * 4;  // 0..60
  const int tj = (tid & 7) * 4;   // 0..28
  float c[4][4] = {};

  for (int kb = 0; kb < 512; kb += 32) {
    __syncthreads();
#pragma unroll
    for (int p = 0; p < 4; ++p) {  // X tile 64x32
      int idx = tid + p * 128;
      int row = idx >> 3, kc = (idx & 7) * 4;
      *(float4*)(Xs + row * 36 + kc) = *(const float4*)(X + (m0 + row) * 512 + kb + kc);
    }
#pragma unroll
    for (int p = 0; p < 2; ++p) {  // W tile 32x32
      int idx = tid + p * 128;
      int row = idx >> 3, kc = (idx & 7) * 4;
      *(float4*)(Ws + row * 36 + kc) = *(const float4*)(W + (u0 + row) * 512 + kb + kc);
    }
    __syncthreads();
#pragma unroll
    for (int kk = 0; kk < 32; kk += 4) {
      float4 a[4], b[4];
#pragma unroll
      for (int i = 0; i < 4; ++i) a[i] = *(const float4*)(Xs + (ti + i) * 36 + kk);
#pragma unroll
      for (int j = 0; j < 4; ++j) b[j] = *(const float4*)(Ws + (tj + j) * 36 + kk);
#pragma unroll
      for (int i = 0; i < 4; ++i)
#pragma unroll
        for (int j = 0; j < 4; ++j) {
          c[i][j] = fmaf(a[i].x, b[j].x, c[i][j]);
          c[i][j] = fmaf(a[i].y, b[j].y, c[i][j]);
          c[i][j] = fmaf(a[i].z, b[j].z, c[i][j]);
          c[i][j] = fmaf(a[i].w, b[j].w, c[i][j]);
        }
    }
  }

  float e[4][4];
#pragma unroll
  for (int i = 0; i < 4; ++i)
#pragma unroll
    for (int j = 0; j < 4; ++j) e[i][j] = __expf(2.f * c[i][j]);

  if (qpart) {
#pragma unroll
    for (int i = 0; i < 4; ++i)
      *(float4*)(Eq + (m0 + ti + i) * 256 + u0 + tj) =
          make_float4(e[i][0], e[i][1], e[i][2], e[i][3]);
  } else {
    int g = m0 + ti;              // key row
    int b = g >> 10, j0 = g & 1023;
#pragma unroll
    for (int jj = 0; jj < 4; ++jj)
      *(float4*)(EkT + b * 262144 + (u0 + tj + jj) * 1024 + j0) =
          make_float4(e[0][jj], e[1][jj], e[2][jj], e[3][jj]);
  }
}

__device__ __forceinline__ float block_reduce16(float v, int op, float* red) {
  // 1024 threads = 16 waves
#pragma unroll
  for (int off = 32; off > 0; off >>= 1) {
    float o = __shfl_xor(v, off, 64);
    v = op ? fmaxf(v, o) : (v + o);
  }
  __syncthreads();  // also separates reuse of red across calls
  if ((threadIdx.x & 63) == 0) red[threadIdx.x >> 6] = v;
  __syncthreads();
  float r = red[0];
#pragma unroll
  for (int i = 1; i < 16; ++i) r = op ? fmaxf(r, red[i]) : (r + red[i]);
  return r;
}

__global__ __launch_bounds__(1024) void scores_softmax(
    const float* __restrict__ Eq, const float* __restrict__ EkT,
    const float* __restrict__ vvec, const int* __restrict__ valid_len,
    float* __restrict__ attn) {
  // one block per (b, pair of query rows); 1024 threads, thread t = column j
  __shared__ float4 QV[256];  // (Eq_row0, Eq_row1, -2*v, 0)
  __shared__ float red[16];
  const int tid = threadIdx.x;
  const int b = blockIdx.x >> 6;
  const int i0 = (blockIdx.x & 63) * 2;
  const int vl = valid_len[b];

  float vv = 0.f;
  if (tid < 256) {
    vv = vvec[tid];
    QV[tid] = make_float4(Eq[(b * 128 + i0) * 256 + tid],
                          Eq[(b * 128 + i0 + 1) * 256 + tid], -2.f * vv, 0.f);
  }
  const float SV = block_reduce16(vv, 0, red);  // sync also publishes QV

  const int j = tid;
  float s0 = -1e6f, s1 = -1e6f;
  if (j < vl) {
    float a0 = 0.f, a1 = 0.f;
    const float* kp = EkT + b * 262144 + j;
#pragma unroll 8
    for (int u = 0; u < 256; ++u) {
      float ek = kp[u << 10];  // coalesced across lanes
      float4 q = QV[u];        // LDS broadcast (free)
      float r0 = __builtin_amdgcn_rcpf(fmaf(q.x, ek, 1.f));
      float r1 = __builtin_amdgcn_rcpf(fmaf(q.y, ek, 1.f));
      a0 = fmaf(q.z, r0, a0);
      a1 = fmaf(q.z, r1, a1);
    }
    s0 = SV + a0;
    s1 = SV + a1;
  }

  float M0 = block_reduce16(s0, 1, red);
  float p0 = (j < vl) ? __expf(s0 - M0) : 0.f;
  float S0 = block_reduce16(p0, 0, red);
  attn[(b * 128 + i0) * 1024 + j] = p0 * __builtin_amdgcn_rcpf(S0);

  float M1 = block_reduce16(s1, 1, red);
  float p1 = (j < vl) ? __expf(s1 - M1) : 0.f;
  float S1 = block_reduce16(p1, 0, red);
  attn[(b * 128 + i0 + 1) * 1024 + j] = p1 * __builtin_amdgcn_rcpf(S1);
}

__global__ __launch_bounds__(64) void attn_value(
    const float* __restrict__ attn, const float* __restrict__ value,
    const int* __restrict__ valid_len, float* __restrict__ out) {
  // one wave per block: 4 rows x 64 cols, no barriers. grid = 4b x 32rg x 8nc
  const int bid = blockIdx.x;
  const int b = bid >> 8;
  const int rg = (bid >> 3) & 31;
  const int nc = bid & 7;
  const int i0 = rg * 4;
  const int lane = threadIdx.x;
  const int vl = valid_len[b];
  const float* A = attn + (b * 128 + i0) * 1024;  // uniform -> scalar loads
  const float* V = value + b * 524288 + nc * 64 + lane;
  float acc0 = 0.f, acc1 = 0.f, acc2 = 0.f, acc3 = 0.f;

  int k = 0;
  for (; k + 8 <= vl; k += 8) {
#pragma unroll
    for (int t = 0; t < 8; ++t) {
      float vx = V[(k + t) * 512];
      acc0 = fmaf(A[0 * 1024 + k + t], vx, acc0);
      acc1 = fmaf(A[1 * 1024 + k + t], vx, acc1);
      acc2 = fmaf(A[2 * 1024 + k + t], vx, acc2);
      acc3 = fmaf(A[3 * 1024 + k + t], vx, acc3);
    }
  }
  for (; k < vl; ++k) {
    float vx = V[k * 512];
    acc0 = fmaf(A[0 * 1024 + k], vx, acc0);
    acc1 = fmaf(A[1 * 1024 + k], vx, acc1);
    acc2 = fmaf(A[2 * 1024 + k], vx, acc2);
    acc3 = fmaf(A[3 * 1024 + k], vx, acc3);
  }
  float* O = out + (b * 128 + i0) * 512 + nc * 64 + lane;
  O[0] = acc0;
  O[512] = acc1;
  O[1024] = acc2;
  O[1536] = acc3;
}

extern "C" void kernel_launch(void* const* d_in, const int* in_sizes, int n_in,
                              void* d_out, int out_size, void* d_ws, size_t ws_size,
                              hipStream_t stream) {
  const float* query = (const float*)d_in[0];
  const float* key   = (const float*)d_in[1];
  const float* value = (const float*)d_in[2];
  const int*   vlen  = (const int*)d_in[3];
  const float* W_q   = (const float*)d_in[4];
  const float* W_k   = (const float*)d_in[5];
  const float* v     = (const float*)d_in[6];
  float* out = (float*)d_out;

  float* ws  = (float*)d_ws;
  float* Eq   = ws + EQ_OFF;    // 512x256
  float* EkT  = ws + EKT_OFF;   // 4x256x1024
  float* attn = ws + ATTN_OFF;  // 4x128x1024

  proj_gemm<<<dim3(72, 8), 128, 0, stream>>>(query, key, W_q, W_k, Eq, EkT);
  scores_softmax<<<256, 1024, 0, stream>>>(Eq, EkT, v, vlen, attn);
  attn_value<<<1024, 64, 0, stream>>>(attn, value, vlen, out);
}

// Round 3
// 160.566 us; speedup vs baseline: 1.6308x; 1.0571x over previous
//
#include <hip/hip_runtime.h>

// MLPAttention B=4, LQ=128, LK=1024, D=512, U=256, fp32.
// scores(i,j) = sum_u v_u * tanh(q_iu + k_uj);  tanh(x) = 1 - 2/(1+e^{2x})
// => scores = SV - 2*sum_u v_u/(1 + Eq_iu*Ek_uj),  Eq=e^{2q}, Ek=e^{2k}
// K1: fused projection GEMM, swizzled LDS (conflict-free), reg-prefetch dbuf,
//     epilogue exp(2x) -> Eq[512][256], EkT[4][256][1024].
// K2: scores + masked softmax fused (1024 thr/block).
// K3: out = attn @ value, 4-way K-split per block + LDS reduce.

#define EQ_OFF   0
#define EKT_OFF  (512 * 256)
#define ATTN_OFF (EKT_OFF + 4 * 256 * 1024)

// swizzled LDS offset for element (row, k) in a 64x32 tile, no padding:
// bank-group = (k/4 + row) mod 8 -> conflict-free strided-row reads.
__device__ __forceinline__ int swz(int row, int k) {
  return row * 32 + ((k + 4 * (row & 7)) & 31);
}

__global__ __launch_bounds__(512) void proj_gemm(
    const float* __restrict__ query, const float* __restrict__ key,
    const float* __restrict__ W_q, const float* __restrict__ W_k,
    float* __restrict__ Eq, float* __restrict__ EkT) {
  // BM=64, BN=64, BK=32, 512 threads (8 waves), 2x4 cyclic microtile.
  __shared__ float Xs[64 * 32];
  __shared__ float Ws[64 * 32];
  const int tid = threadIdx.x;
  const bool qpart = blockIdx.x < 8;
  const float* X = qpart ? query : key;
  const float* W = qpart ? W_q : W_k;
  const int m0 = (qpart ? blockIdx.x : (blockIdx.x - 8)) * 64;
  const int u0 = blockIdx.y * 64;
  const int tx = tid & 15;        // col base (cyclic +16)
  const int ty = tid >> 4;        // row base (cyclic +32), 0..31
  // staging indices: each thread loads one float4 of X-tile and one of W-tile
  const int lrow = tid >> 3;           // 0..63
  const int lkc = (tid & 7) * 4;       // 0..28
  const float* Xg = X + (m0 + lrow) * 512 + lkc;
  const float* Wg = W + (u0 + lrow) * 512 + lkc;
  const int ldst = swz(lrow, lkc);

  float c[2][4] = {};
  float4 rx = *(const float4*)(Xg);
  float4 rw = *(const float4*)(Wg);

  for (int kb = 0; kb < 16; ++kb) {
    *(float4*)(Xs + ldst) = rx;
    *(float4*)(Ws + ldst) = rw;
    __syncthreads();
    if (kb + 1 < 16) {
      rx = *(const float4*)(Xg + (kb + 1) * 32);
      rw = *(const float4*)(Wg + (kb + 1) * 32);
    }
#pragma unroll
    for (int kk = 0; kk < 32; kk += 4) {
      float4 a0 = *(const float4*)(Xs + swz(ty, kk));
      float4 a1 = *(const float4*)(Xs + swz(ty + 32, kk));
      float4 b[4];
#pragma unroll
      for (int j = 0; j < 4; ++j) b[j] = *(const float4*)(Ws + swz(tx + 16 * j, kk));
#pragma unroll
      for (int j = 0; j < 4; ++j) {
        c[0][j] = fmaf(a0.x, b[j].x, c[0][j]);
        c[0][j] = fmaf(a0.y, b[j].y, c[0][j]);
        c[0][j] = fmaf(a0.z, b[j].z, c[0][j]);
        c[0][j] = fmaf(a0.w, b[j].w, c[0][j]);
        c[1][j] = fmaf(a1.x, b[j].x, c[1][j]);
        c[1][j] = fmaf(a1.y, b[j].y, c[1][j]);
        c[1][j] = fmaf(a1.z, b[j].z, c[1][j]);
        c[1][j] = fmaf(a1.w, b[j].w, c[1][j]);
      }
    }
    __syncthreads();
  }

  float e[2][4];
#pragma unroll
  for (int i = 0; i < 2; ++i)
#pragma unroll
    for (int j = 0; j < 4; ++j) e[i][j] = __expf(2.f * c[i][j]);

  if (qpart) {
#pragma unroll
    for (int j = 0; j < 4; ++j) {
      Eq[(m0 + ty) * 256 + u0 + tx + 16 * j] = e[0][j];
      Eq[(m0 + ty + 32) * 256 + u0 + tx + 16 * j] = e[1][j];
    }
  } else {
    int g = (blockIdx.x - 8) * 64 + ty;  // key row
    int b = g >> 10, j0 = g & 1023;
#pragma unroll
    for (int j = 0; j < 4; ++j) {
      int col = u0 + tx + 16 * j;
      EkT[b * 262144 + col * 1024 + j0] = e[0][j];
      EkT[b * 262144 + col * 1024 + j0 + 32] = e[1][j];
    }
  }
}

__device__ __forceinline__ float block_reduce16(float v, int op, float* red) {
#pragma unroll
  for (int off = 32; off > 0; off >>= 1) {
    float o = __shfl_xor(v, off, 64);
    v = op ? fmaxf(v, o) : (v + o);
  }
  __syncthreads();
  if ((threadIdx.x & 63) == 0) red[threadIdx.x >> 6] = v;
  __syncthreads();
  float r = red[0];
#pragma unroll
  for (int i = 1; i < 16; ++i) r = op ? fmaxf(r, red[i]) : (r + red[i]);
  return r;
}

__global__ __launch_bounds__(1024) void scores_softmax(
    const float* __restrict__ Eq, const float* __restrict__ EkT,
    const float* __restrict__ vvec, const int* __restrict__ valid_len,
    float* __restrict__ attn) {
  __shared__ float4 QV[256];  // (Eq_row0, Eq_row1, -2*v, 0)
  __shared__ float red[16];
  const int tid = threadIdx.x;
  const int b = blockIdx.x >> 6;
  const int i0 = (blockIdx.x & 63) * 2;
  const int vl = valid_len[b];

  float vv = 0.f;
  if (tid < 256) {
    vv = vvec[tid];
    QV[tid] = make_float4(Eq[(b * 128 + i0) * 256 + tid],
                          Eq[(b * 128 + i0 + 1) * 256 + tid], -2.f * vv, 0.f);
  }
  const float SV = block_reduce16(vv, 0, red);  // sync also publishes QV

  const int j = tid;
  float s0 = -1e6f, s1 = -1e6f;
  if (j < vl) {
    float a0 = 0.f, a1 = 0.f;
    const float* kp = EkT + b * 262144 + j;
#pragma unroll 8
    for (int u = 0; u < 256; ++u) {
      float ek = kp[u << 10];  // coalesced across lanes
      float4 q = QV[u];        // LDS broadcast (free)
      float r0 = __builtin_amdgcn_rcpf(fmaf(q.x, ek, 1.f));
      float r1 = __builtin_amdgcn_rcpf(fmaf(q.y, ek, 1.f));
      a0 = fmaf(q.z, r0, a0);
      a1 = fmaf(q.z, r1, a1);
    }
    s0 = SV + a0;
    s1 = SV + a1;
  }

  float M0 = block_reduce16(s0, 1, red);
  float p0 = (j < vl) ? __expf(s0 - M0) : 0.f;
  float S0 = block_reduce16(p0, 0, red);
  attn[(b * 128 + i0) * 1024 + j] = p0 * __builtin_amdgcn_rcpf(S0);

  float M1 = block_reduce16(s1, 1, red);
  float p1 = (j < vl) ? __expf(s1 - M1) : 0.f;
  float S1 = block_reduce16(p1, 0, red);
  attn[(b * 128 + i0 + 1) * 1024 + j] = p1 * __builtin_amdgcn_rcpf(S1);
}

__global__ __launch_bounds__(256) void attn_value(
    const float* __restrict__ attn, const float* __restrict__ value,
    const int* __restrict__ valid_len, float* __restrict__ out) {
  // grid = 4b x 16 rowgroups x 8 colgroups = 512 blocks, 256 thr (4 waves).
  // Each wave handles a K-quarter for 8 rows x 64 cols; LDS reduce at end.
  __shared__ float red[4][8][64];
  const int bid = blockIdx.x;
  const int b = bid >> 7;
  const int rg = (bid >> 3) & 15;
  const int cg = bid & 7;
  const int i0 = rg * 8;
  const int w = threadIdx.x >> 6;
  const int lane = threadIdx.x & 63;
  const int vl = valid_len[b];
  const float* A = attn + (b * 128 + i0) * 1024;  // wave-uniform indexing
  const float* V = value + b * 524288 + cg * 64 + lane;

  float acc[8] = {};
  const int ks = w * 256;
  const int ke = min(ks + 256, vl);
  int k = ks;
  for (; k + 8 <= ke; k += 8) {
#pragma unroll
    for (int t = 0; t < 8; ++t) {
      float vx = V[(k + t) * 512];
#pragma unroll
      for (int r = 0; r < 8; ++r) acc[r] = fmaf(A[r * 1024 + k + t], vx, acc[r]);
    }
  }
  for (; k < ke; ++k) {
    float vx = V[k * 512];
#pragma unroll
    for (int r = 0; r < 8; ++r) acc[r] = fmaf(A[r * 1024 + k], vx, acc[r]);
  }

#pragma unroll
  for (int r = 0; r < 8; ++r) red[w][r][lane] = acc[r];
  __syncthreads();
  const int r0 = threadIdx.x >> 6;
#pragma unroll
  for (int p = 0; p < 2; ++p) {
    int r = r0 + p * 4;
    float s = red[0][r][lane] + red[1][r][lane] + red[2][r][lane] + red[3][r][lane];
    out[(b * 128 + i0 + r) * 512 + cg * 64 + lane] = s;
  }
}

extern "C" void kernel_launch(void* const* d_in, const int* in_sizes, int n_in,
                              void* d_out, int out_size, void* d_ws, size_t ws_size,
                              hipStream_t stream) {
  const float* query = (const float*)d_in[0];
  const float* key   = (const float*)d_in[1];
  const float* value = (const float*)d_in[2];
  const int*   vlen  = (const int*)d_in[3];
  const float* W_q   = (const float*)d_in[4];
  const float* W_k   = (const float*)d_in[5];
  const float* v     = (const float*)d_in[6];
  float* out = (float*)d_out;

  float* ws   = (float*)d_ws;
  float* Eq   = ws + EQ_OFF;    // 512x256
  float* EkT  = ws + EKT_OFF;   // 4x256x1024
  float* attn = ws + ATTN_OFF;  // 4x128x1024

  proj_gemm<<<dim3(72, 4), 512, 0, stream>>>(query, key, W_q, W_k, Eq, EkT);
  scores_softmax<<<256, 1024, 0, stream>>>(Eq, EkT, v, vlen, attn);
  attn_value<<<512, 256, 0, stream>>>(attn, value, vlen, out);
}

// Round 4
// 156.947 us; speedup vs baseline: 1.6684x; 1.0231x over previous
//
#include <hip/hip_runtime.h>

// MLPAttention B=4, LQ=128, LK=1024, D=512, U=256, fp32.
// scores(i,j) = sum_u v_u * tanh(q_iu + k_uj);  tanh(x) = 1 - 2/(1+e^{2x})
// => scores = SV - 2*sum_u v_u/(1 + Eq_iu*Ek_uj),  Eq=e^{2q}, Ek=e^{2k}
// K1 proj_gemm: fp32 vector GEMM, 2-way K-split, 4x4 microtile (FMA:LDS = 64:8
//    per 4-K step -> compute-bound), early-exit for masked key tiles.
// K2 combine_exp: EkT = exp(2(P0+P1)) in-place, same for Eq.
// K3 scores_softmax: fused scores + masked softmax (unchanged this round).
// K4 attn_value: 8-way K-split per block, LDS reduce.

#define PQ0_OFF  0                        // 512*256, becomes Eq after combine
#define PQ1_OFF  (512 * 256)
#define PKT0_OFF (2 * 512 * 256)          // 4*256*1024, becomes EkT
#define PKT1_OFF (PKT0_OFF + 4 * 256 * 1024)
#define ATTN_OFF (PKT1_OFF + 4 * 256 * 1024)

// swizzled LDS offset for (row, k) in a 64x32 tile: bank-group = (k/4+row)%8
__device__ __forceinline__ int swz(int row, int k) {
  return row * 32 + ((k + 4 * (row & 7)) & 31);
}

__global__ __launch_bounds__(256) void proj_gemm(
    const float* __restrict__ query, const float* __restrict__ key,
    const float* __restrict__ W_q, const float* __restrict__ W_k,
    const int* __restrict__ vlen, float* __restrict__ Pq,
    float* __restrict__ PkT) {
  // BM=64, BN=64, K-half=256 (BK=32 x 8 tiles), 256 thr, 4x4 microtile.
  __shared__ float Xs[64 * 32];
  __shared__ float Ws[64 * 32];
  const int tid = threadIdx.x;
  const int bid = blockIdx.x;
  const int ks = bid & 1;
  const int rest = bid >> 1;
  const int mb = rest >> 2;  // 0..71: 0..7 = query rows, 8..71 = key rows
  const int uc = rest & 3;
  const bool qpart = mb < 8;
  const int m0 = (qpart ? mb : mb - 8) * 64;
  const int u0 = uc * 64;
  int kbatch = 0, j0base = 0;
  if (!qpart) {
    kbatch = m0 >> 10;
    j0base = m0 & 1023;
    if (j0base >= vlen[kbatch]) return;  // fully masked tile: skip
  }
  const float* X = (qpart ? query : key) + (size_t)m0 * 512 + ks * 256;
  const float* W = (qpart ? W_q : W_k) + ks * 256;

  const int l0row = tid >> 3, lkc = (tid & 7) * 4;
  const int l1row = l0row + 32;
  const float* Xg0 = X + l0row * 512 + lkc;
  const float* Xg1 = X + l1row * 512 + lkc;
  const float* Wg0 = W + (u0 + l0row) * 512 + lkc;
  const float* Wg1 = W + (u0 + l1row) * 512 + lkc;
  const int d0 = swz(l0row, lkc), d1 = swz(l1row, lkc);

  const int ti = (tid >> 4) * 4;  // 4 unique per wave -> 16-way broadcast
  const int tj = (tid & 15) * 4;  // 16 unique per wave
  float c[4][4] = {};

  float4 rx0 = *(const float4*)Xg0;
  float4 rx1 = *(const float4*)Xg1;
  float4 rw0 = *(const float4*)Wg0;
  float4 rw1 = *(const float4*)Wg1;

  for (int kb = 0; kb < 8; ++kb) {
    *(float4*)(Xs + d0) = rx0;
    *(float4*)(Xs + d1) = rx1;
    *(float4*)(Ws + d0) = rw0;
    *(float4*)(Ws + d1) = rw1;
    __syncthreads();
    if (kb + 1 < 8) {
      rx0 = *(const float4*)(Xg0 + (kb + 1) * 32);
      rx1 = *(const float4*)(Xg1 + (kb + 1) * 32);
      rw0 = *(const float4*)(Wg0 + (kb + 1) * 32);
      rw1 = *(const float4*)(Wg1 + (kb + 1) * 32);
    }
#pragma unroll
    for (int kk = 0; kk < 32; kk += 4) {
      float4 a[4], b[4];
#pragma unroll
      for (int i = 0; i < 4; ++i) a[i] = *(const float4*)(Xs + swz(ti + i, kk));
#pragma unroll
      for (int j = 0; j < 4; ++j) b[j] = *(const float4*)(Ws + swz(tj + j, kk));
#pragma unroll
      for (int i = 0; i < 4; ++i)
#pragma unroll
        for (int j = 0; j < 4; ++j) {
          c[i][j] = fmaf(a[i].x, b[j].x, c[i][j]);
          c[i][j] = fmaf(a[i].y, b[j].y, c[i][j]);
          c[i][j] = fmaf(a[i].z, b[j].z, c[i][j]);
          c[i][j] = fmaf(a[i].w, b[j].w, c[i][j]);
        }
    }
    __syncthreads();
  }

  if (qpart) {
    float* Pout = Pq + ks * 131072;
#pragma unroll
    for (int i = 0; i < 4; ++i)
      *(float4*)(Pout + (m0 + ti + i) * 256 + u0 + tj) =
          make_float4(c[i][0], c[i][1], c[i][2], c[i][3]);
  } else {
    float* Pout = PkT + ks * 1048576 + kbatch * 262144;
#pragma unroll
    for (int j = 0; j < 4; ++j)  // ti is contiguous in j-dim -> float4 store
      *(float4*)(Pout + (u0 + tj + j) * 1024 + j0base + ti) =
          make_float4(c[0][j], c[1][j], c[2][j], c[3][j]);
  }
}

__global__ __launch_bounds__(256) void combine_exp(float* __restrict__ ws) {
  const float4* Pk0 = (const float4*)(ws + PKT0_OFF);
  const float4* Pk1 = (const float4*)(ws + PKT1_OFF);
  float4* Ek = (float4*)(ws + PKT0_OFF);  // in-place
  const float4* Pq0 = (const float4*)(ws + PQ0_OFF);
  const float4* Pq1 = (const float4*)(ws + PQ1_OFF);
  float4* Eq = (float4*)(ws + PQ0_OFF);  // in-place
  const int idx = blockIdx.x * 256 + threadIdx.x;
  if (idx < 262144) {
    float4 a = Pk0[idx], b = Pk1[idx];
    Ek[idx] = make_float4(__expf(2.f * (a.x + b.x)), __expf(2.f * (a.y + b.y)),
                          __expf(2.f * (a.z + b.z)), __expf(2.f * (a.w + b.w)));
  } else {
    const int i2 = idx - 262144;
    float4 a = Pq0[i2], b = Pq1[i2];
    Eq[i2] = make_float4(__expf(2.f * (a.x + b.x)), __expf(2.f * (a.y + b.y)),
                         __expf(2.f * (a.z + b.z)), __expf(2.f * (a.w + b.w)));
  }
}

__device__ __forceinline__ float block_reduce16(float v, int op, float* red) {
#pragma unroll
  for (int off = 32; off > 0; off >>= 1) {
    float o = __shfl_xor(v, off, 64);
    v = op ? fmaxf(v, o) : (v + o);
  }
  __syncthreads();
  if ((threadIdx.x & 63) == 0) red[threadIdx.x >> 6] = v;
  __syncthreads();
  float r = red[0];
#pragma unroll
  for (int i = 1; i < 16; ++i) r = op ? fmaxf(r, red[i]) : (r + red[i]);
  return r;
}

__global__ __launch_bounds__(1024) void scores_softmax(
    const float* __restrict__ Eq, const float* __restrict__ EkT,
    const float* __restrict__ vvec, const int* __restrict__ valid_len,
    float* __restrict__ attn) {
  __shared__ float4 QV[256];  // (Eq_row0, Eq_row1, -2*v, 0)
  __shared__ float red[16];
  const int tid = threadIdx.x;
  const int b = blockIdx.x >> 6;
  const int i0 = (blockIdx.x & 63) * 2;
  const int vl = valid_len[b];

  float vv = 0.f;
  if (tid < 256) {
    vv = vvec[tid];
    QV[tid] = make_float4(Eq[(b * 128 + i0) * 256 + tid],
                          Eq[(b * 128 + i0 + 1) * 256 + tid], -2.f * vv, 0.f);
  }
  const float SV = block_reduce16(vv, 0, red);  // sync also publishes QV

  const int j = tid;
  float s0 = -1e6f, s1 = -1e6f;
  if (j < vl) {
    float a0 = 0.f, a1 = 0.f;
    const float* kp = EkT + b * 262144 + j;
#pragma unroll 8
    for (int u = 0; u < 256; ++u) {
      float ek = kp[u << 10];  // coalesced across lanes
      float4 q = QV[u];        // LDS broadcast (free)
      float r0 = __builtin_amdgcn_rcpf(fmaf(q.x, ek, 1.f));
      float r1 = __builtin_amdgcn_rcpf(fmaf(q.y, ek, 1.f));
      a0 = fmaf(q.z, r0, a0);
      a1 = fmaf(q.z, r1, a1);
    }
    s0 = SV + a0;
    s1 = SV + a1;
  }

  float M0 = block_reduce16(s0, 1, red);
  float p0 = (j < vl) ? __expf(s0 - M0) : 0.f;
  float S0 = block_reduce16(p0, 0, red);
  attn[(b * 128 + i0) * 1024 + j] = p0 * __builtin_amdgcn_rcpf(S0);

  float M1 = block_reduce16(s1, 1, red);
  float p1 = (j < vl) ? __expf(s1 - M1) : 0.f;
  float S1 = block_reduce16(p1, 0, red);
  attn[(b * 128 + i0 + 1) * 1024 + j] = p1 * __builtin_amdgcn_rcpf(S1);
}

__global__ __launch_bounds__(512) void attn_value(
    const float* __restrict__ attn, const float* __restrict__ value,
    const int* __restrict__ valid_len, float* __restrict__ out) {
  // grid = 4b x 16 rowgroups x 8 colgroups = 512 blocks, 512 thr (8 waves).
  // Each wave handles a K-eighth for 8 rows x 64 cols; LDS reduce at end.
  __shared__ float red[8][8][64];
  const int bid = blockIdx.x;
  const int b = bid >> 7;
  const int rg = (bid >> 3) & 15;
  const int cg = bid & 7;
  const int i0 = rg * 8;
  const int w = threadIdx.x >> 6;
  const int lane = threadIdx.x & 63;
  const int vl = valid_len[b];
  const float* A = attn + (b * 128 + i0) * 1024;  // wave-uniform -> s_load
  const float* V = value + b * 524288 + cg * 64 + lane;

  float acc[8] = {};
  const int kstart = w * 128;
  const int kend = min(kstart + 128, vl);
  int k = kstart;
  for (; k + 8 <= kend; k += 8) {
#pragma unroll
    for (int t = 0; t < 8; ++t) {
      float vx = V[(k + t) * 512];
#pragma unroll
      for (int r = 0; r < 8; ++r) acc[r] = fmaf(A[r * 1024 + k + t], vx, acc[r]);
    }
  }
  for (; k < kend; ++k) {
    float vx = V[k * 512];
#pragma unroll
    for (int r = 0; r < 8; ++r) acc[r] = fmaf(A[r * 1024 + k], vx, acc[r]);
  }

#pragma unroll
  for (int r = 0; r < 8; ++r) red[w][r][lane] = acc[r];
  __syncthreads();
  const int r = threadIdx.x >> 6;
  float s = 0.f;
#pragma unroll
  for (int ww = 0; ww < 8; ++ww) s += red[ww][r][lane];
  out[(b * 128 + i0 + r) * 512 + cg * 64 + lane] = s;
}

extern "C" void kernel_launch(void* const* d_in, const int* in_sizes, int n_in,
                              void* d_out, int out_size, void* d_ws, size_t ws_size,
                              hipStream_t stream) {
  const float* query = (const float*)d_in[0];
  const float* key   = (const float*)d_in[1];
  const float* value = (const float*)d_in[2];
  const int*   vlen  = (const int*)d_in[3];
  const float* W_q   = (const float*)d_in[4];
  const float* W_k   = (const float*)d_in[5];
  const float* v     = (const float*)d_in[6];
  float* out = (float*)d_out;

  float* ws   = (float*)d_ws;
  float* Pq   = ws + PQ0_OFF;
  float* PkT  = ws + PKT0_OFF;
  float* attn = ws + ATTN_OFF;

  proj_gemm<<<576, 256, 0, stream>>>(query, key, W_q, W_k, vlen, Pq, PkT);
  combine_exp<<<1152, 256, 0, stream>>>(ws);
  scores_softmax<<<256, 1024, 0, stream>>>(Pq, PkT, v, vlen, attn);
  attn_value<<<512, 512, 0, stream>>>(attn, value, vlen, out);
}

// Round 5
// 125.392 us; speedup vs baseline: 2.0883x; 1.2517x over previous
//
#include <hip/hip_runtime.h>

// MLPAttention B=4, LQ=128, LK=1024, D=512, U=256, fp32.
// scores(i,j) = sum_u v_u * tanh(q_iu + k_uj);  tanh(x) = 1 - 2/(1+e^{2x})
// => scores = SV - 2*sum_u v_u/(1 + Eq_iu*Ek_uj),  Eq=e^{2q}, Ek=e^{2k}
// K1 proj_mfma: fp16 MFMA NT-GEMM (fp32->fp16 staged in LDS, fp32 acc),
//    epilogue exp(2x). q-part: C[m][u] -> Eq. k-part: C[u][j] -> EkT
//    (A=W_k, B=key so transposed store is coalesced). Masked-tile early-exit.
// K2 scores_softmax: fused scores + masked softmax (1024 thr).
// K3 attn_value: 8-way K-split per block, LDS reduce.

typedef _Float16 half8 __attribute__((ext_vector_type(8)));
typedef float floatx4 __attribute__((ext_vector_type(4)));

#define EQ_OFF   0
#define EKT_OFF  (512 * 256)
#define ATTN_OFF (EKT_OFF + 4 * 256 * 1024)

__global__ __launch_bounds__(256) void proj_mfma(
    const float* __restrict__ query, const float* __restrict__ key,
    const float* __restrict__ W_q, const float* __restrict__ W_k,
    const int* __restrict__ vlen, float* __restrict__ Eq,
    float* __restrict__ EkT) {
  // 64(M) x 64(N) tile, K=512 in 16 steps of BK=32. 256 thr = 4 waves (2x2).
  __shared__ __align__(16) _Float16 As[64 * 32];
  __shared__ __align__(16) _Float16 Bs[64 * 32];
  const int tid = threadIdx.x;
  const int mb = blockIdx.x;   // 0..7 q-part (m-tiles), 8..71 k-part (j-tiles)
  const int u0 = blockIdx.y * 64;
  const bool qpart = mb < 8;
  const float *Ag, *Bg;
  int kbatch = 0, j0 = 0, m0 = 0;
  if (qpart) {
    m0 = mb * 64;
    Ag = query + (size_t)m0 * 512;   // A rows = query rows (M = m)
    Bg = W_q + (size_t)u0 * 512;     // B rows = W_q rows   (N = u)
  } else {
    const int g0 = (mb - 8) * 64;
    kbatch = g0 >> 10;
    j0 = g0 & 1023;
    if (j0 >= vlen[kbatch]) return;  // fully-masked key tile
    Ag = W_k + (size_t)u0 * 512;     // A rows = W_k rows (M = u)
    Bg = key + (size_t)g0 * 512;     // B rows = key rows (N = j)
  }

  // staging: thread -> (row = tid>>2, 8-float quarter = (tid&3)*8)
  const int lrow = tid >> 2, lkq = (tid & 3) * 8;
  const float* Ags = Ag + lrow * 512 + lkq;
  const float* Bgs = Bg + lrow * 512 + lkq;
  _Float16* Ads = As + lrow * 32 + lkq;
  _Float16* Bds = Bs + lrow * 32 + lkq;

  const int lane = tid & 63;
  const int wid = tid >> 6;
  const int wm = (wid & 1) * 32, wn = (wid >> 1) * 32;
  const int frow = lane & 15;
  const int fk = (lane >> 4) * 8;

  floatx4 acc[2][2] = {{{0.f, 0.f, 0.f, 0.f}, {0.f, 0.f, 0.f, 0.f}},
                       {{0.f, 0.f, 0.f, 0.f}, {0.f, 0.f, 0.f, 0.f}}};

  float4 ra0 = *(const float4*)Ags;
  float4 ra1 = *(const float4*)(Ags + 4);
  float4 rb0 = *(const float4*)Bgs;
  float4 rb1 = *(const float4*)(Bgs + 4);

  for (int kb = 0; kb < 16; ++kb) {
    half8 ha, hb;
    ha[0] = (_Float16)ra0.x; ha[1] = (_Float16)ra0.y;
    ha[2] = (_Float16)ra0.z; ha[3] = (_Float16)ra0.w;
    ha[4] = (_Float16)ra1.x; ha[5] = (_Float16)ra1.y;
    ha[6] = (_Float16)ra1.z; ha[7] = (_Float16)ra1.w;
    hb[0] = (_Float16)rb0.x; hb[1] = (_Float16)rb0.y;
    hb[2] = (_Float16)rb0.z; hb[3] = (_Float16)rb0.w;
    hb[4] = (_Float16)rb1.x; hb[5] = (_Float16)rb1.y;
    hb[6] = (_Float16)rb1.z; hb[7] = (_Float16)rb1.w;
    __syncthreads();  // prior iter's fragment reads complete
    *(half8*)Ads = ha;
    *(half8*)Bds = hb;
    __syncthreads();
    if (kb + 1 < 16) {
      ra0 = *(const float4*)(Ags + (kb + 1) * 32);
      ra1 = *(const float4*)(Ags + (kb + 1) * 32 + 4);
      rb0 = *(const float4*)(Bgs + (kb + 1) * 32);
      rb1 = *(const float4*)(Bgs + (kb + 1) * 32 + 4);
    }
    half8 a0 = *(const half8*)(As + (wm + frow) * 32 + fk);
    half8 a1 = *(const half8*)(As + (wm + 16 + frow) * 32 + fk);
    half8 b0 = *(const half8*)(Bs + (wn + frow) * 32 + fk);
    half8 b1 = *(const half8*)(Bs + (wn + 16 + frow) * 32 + fk);
    acc[0][0] = __builtin_amdgcn_mfma_f32_16x16x32_f16(a0, b0, acc[0][0], 0, 0, 0);
    acc[0][1] = __builtin_amdgcn_mfma_f32_16x16x32_f16(a0, b1, acc[0][1], 0, 0, 0);
    acc[1][0] = __builtin_amdgcn_mfma_f32_16x16x32_f16(a1, b0, acc[1][0], 0, 0, 0);
    acc[1][1] = __builtin_amdgcn_mfma_f32_16x16x32_f16(a1, b1, acc[1][1], 0, 0, 0);
  }

  // C/D layout: col = lane&15, row = (lane>>4)*4 + reg
  const int rbase = (lane >> 4) * 4;
  const int col = lane & 15;
#pragma unroll
  for (int mi = 0; mi < 2; ++mi)
#pragma unroll
    for (int ni = 0; ni < 2; ++ni)
#pragma unroll
      for (int r = 0; r < 4; ++r) {
        const int R = wm + mi * 16 + rbase + r;   // M index
        const int C = wn + ni * 16 + col;         // N index
        const float e = __expf(2.f * acc[mi][ni][r]);
        if (qpart)
          Eq[(m0 + R) * 256 + u0 + C] = e;
        else
          EkT[kbatch * 262144 + (u0 + R) * 1024 + j0 + C] = e;
      }
}

__device__ __forceinline__ float block_reduce16(float v, int op, float* red) {
#pragma unroll
  for (int off = 32; off > 0; off >>= 1) {
    float o = __shfl_xor(v, off, 64);
    v = op ? fmaxf(v, o) : (v + o);
  }
  __syncthreads();
  if ((threadIdx.x & 63) == 0) red[threadIdx.x >> 6] = v;
  __syncthreads();
  float r = red[0];
#pragma unroll
  for (int i = 1; i < 16; ++i) r = op ? fmaxf(r, red[i]) : (r + red[i]);
  return r;
}

__global__ __launch_bounds__(1024) void scores_softmax(
    const float* __restrict__ Eq, const float* __restrict__ EkT,
    const float* __restrict__ vvec, const int* __restrict__ valid_len,
    float* __restrict__ attn) {
  __shared__ float4 QV[256];  // (Eq_row0, Eq_row1, -2*v, 0)
  __shared__ float red[16];
  const int tid = threadIdx.x;
  const int b = blockIdx.x >> 6;
  const int i0 = (blockIdx.x & 63) * 2;
  const int vl = valid_len[b];

  float vv = 0.f;
  if (tid < 256) {
    vv = vvec[tid];
    QV[tid] = make_float4(Eq[(b * 128 + i0) * 256 + tid],
                          Eq[(b * 128 + i0 + 1) * 256 + tid], -2.f * vv, 0.f);
  }
  const float SV = block_reduce16(vv, 0, red);  // sync also publishes QV

  const int j = tid;
  float s0 = -1e6f, s1 = -1e6f;
  if (j < vl) {
    float a0 = 0.f, a1 = 0.f;
    const float* kp = EkT + b * 262144 + j;
#pragma unroll 8
    for (int u = 0; u < 256; ++u) {
      float ek = kp[u << 10];  // coalesced across lanes
      float4 q = QV[u];        // LDS broadcast (free)
      float r0 = __builtin_amdgcn_rcpf(fmaf(q.x, ek, 1.f));
      float r1 = __builtin_amdgcn_rcpf(fmaf(q.y, ek, 1.f));
      a0 = fmaf(q.z, r0, a0);
      a1 = fmaf(q.z, r1, a1);
    }
    s0 = SV + a0;
    s1 = SV + a1;
  }

  float M0 = block_reduce16(s0, 1, red);
  float p0 = (j < vl) ? __expf(s0 - M0) : 0.f;
  float S0 = block_reduce16(p0, 0, red);
  attn[(b * 128 + i0) * 1024 + j] = p0 * __builtin_amdgcn_rcpf(S0);

  float M1 = block_reduce16(s1, 1, red);
  float p1 = (j < vl) ? __expf(s1 - M1) : 0.f;
  float S1 = block_reduce16(p1, 0, red);
  attn[(b * 128 + i0 + 1) * 1024 + j] = p1 * __builtin_amdgcn_rcpf(S1);
}

__global__ __launch_bounds__(512) void attn_value(
    const float* __restrict__ attn, const float* __restrict__ value,
    const int* __restrict__ valid_len, float* __restrict__ out) {
  // grid = 4b x 16 rowgroups x 8 colgroups = 512 blocks, 512 thr (8 waves).
  __shared__ float red[8][8][64];
  const int bid = blockIdx.x;
  const int b = bid >> 7;
  const int rg = (bid >> 3) & 15;
  const int cg = bid & 7;
  const int i0 = rg * 8;
  const int w = threadIdx.x >> 6;
  const int lane = threadIdx.x & 63;
  const int vl = valid_len[b];
  const float* A = attn + (b * 128 + i0) * 1024;  // wave-uniform -> s_load
  const float* V = value + b * 524288 + cg * 64 + lane;

  float acc[8] = {};
  const int kstart = w * 128;
  const int kend = min(kstart + 128, vl);
  int k = kstart;
  for (; k + 8 <= kend; k += 8) {
#pragma unroll
    for (int t = 0; t < 8; ++t) {
      float vx = V[(k + t) * 512];
#pragma unroll
      for (int r = 0; r < 8; ++r) acc[r] = fmaf(A[r * 1024 + k + t], vx, acc[r]);
    }
  }
  for (; k < kend; ++k) {
    float vx = V[k * 512];
#pragma unroll
    for (int r = 0; r < 8; ++r) acc[r] = fmaf(A[r * 1024 + k], vx, acc[r]);
  }

#pragma unroll
  for (int r = 0; r < 8; ++r) red[w][r][lane] = acc[r];
  __syncthreads();
  const int r = threadIdx.x >> 6;
  float s = 0.f;
#pragma unroll
  for (int ww = 0; ww < 8; ++ww) s += red[ww][r][lane];
  out[(b * 128 + i0 + r) * 512 + cg * 64 + lane] = s;
}

extern "C" void kernel_launch(void* const* d_in, const int* in_sizes, int n_in,
                              void* d_out, int out_size, void* d_ws, size_t ws_size,
                              hipStream_t stream) {
  const float* query = (const float*)d_in[0];
  const float* key   = (const float*)d_in[1];
  const float* value = (const float*)d_in[2];
  const int*   vlen  = (const int*)d_in[3];
  const float* W_q   = (const float*)d_in[4];
  const float* W_k   = (const float*)d_in[5];
  const float* v     = (const float*)d_in[6];
  float* out = (float*)d_out;

  float* ws   = (float*)d_ws;
  float* Eq   = ws + EQ_OFF;    // 512x256
  float* EkT  = ws + EKT_OFF;   // 4x256x1024
  float* attn = ws + ATTN_OFF;  // 4x128x1024

  proj_mfma<<<dim3(72, 4), 256, 0, stream>>>(query, key, W_q, W_k, vlen, Eq, EkT);
  scores_softmax<<<256, 1024, 0, stream>>>(Eq, EkT, v, vlen, attn);
  attn_value<<<512, 512, 0, stream>>>(attn, value, vlen, out);
}